// Round 9
// baseline (57.239 us; speedup 1.0000x reference)
//
#include <hip/hip_runtime.h>
#include <math.h>

#define NB     24
#define FBIN   512
#define ROWS   (32*1200)
#define GRID   2048
#define BLK    256
#define WPB    4
#define NWAVES (GRID*WPB)    // 8192 waves; 2 rows/iter
#define SLOTS  20            // stride 80 B -> 16B-aligned b128 reads
#define SCOLP  28            // padded S-column stride (112 B, 16B-aligned)
#define LOG2E  1.44269504f

__device__ __constant__ int   c_off[NB+1] = {0,3,6,9,12,16,20,24,29,34,40,47,55,64,74,86,100,118,140,169,204,246,304,384,512};
__device__ __constant__ float c_k[NB]     = {3,3,3,3,4,4,4,5,5,6,7,8,9,10,12,14,18,22,29,35,42,58,80,128};

#define RDLANE(v,i) __int_as_float(__builtin_amdgcn_readlane(__float_as_int(v), (i)))

__global__ __launch_bounds__(BLK) void pe_main(const float* __restrict__ lm,
                                               const float* __restrict__ re,
                                               const float* __restrict__ im,
                                               const float* __restrict__ S,
                                               float* __restrict__ partial)
{
    __shared__ float s_slot[WPB][2][2][NB*SLOTS];  // [wave][parity][row-of-pair][480] = 30.7 KB
    __shared__ float s_Scol[NB*SCOLP];             // S transposed, column-contiguous
    __shared__ float s_invc[NB];

    const int tid  = threadIdx.x;
    const int w    = tid >> 6;
    const int lane = tid & 63;

    // S -> LDS (column-major, padded); colsum
    for (int i = tid; i < NB*NB; i += BLK) {
        const int r = i / NB, c = i - r*NB;
        s_Scol[c*SCOLP + r] = S[i];
    }
    __syncthreads();
    if (tid < NB) {
        float cs = 1e-8f;
        for (int i = 0; i < NB; ++i) cs += s_Scol[tid*SCOLP + i];
        s_invc[tid] = 1.0f / cs;
    }
    __syncthreads();

    // zero all 4 of this wave's slot buffers (pads stay 0 forever)
    {
        float* sw = &s_slot[w][0][0][0];
        for (int i = lane; i < 2*2*NB*SLOTS; i += 64) sw[i] = 0.f;
    }

    // ---- per-lane row-invariant metadata (8 contiguous bins per lane) ----
    const int bin0 = lane * 8;
    int waddr[8], band4[8];
    float tq[8], a4[8];
    #pragma unroll
    for (int j = 0; j < 8; ++j) {
        const int binj = bin0 + j;
        int b = 0;
        for (int q = 0; q < NB; ++q) if (binj >= c_off[q+1]) b++;
        band4[j] = b << 2;
        waddr[j] = b*SLOTS + (lane - (c_off[b] >> 3));
        const float z = (binj + 1) * 0.03125f;
        tq[j] = 3.64f*__builtin_amdgcn_exp2f(-0.8f*__builtin_amdgcn_logf(z + 1e-6f))
              - 6.5f*__builtin_amdgcn_exp2f(-0.6f*LOG2E*(z-3.3f)*(z-3.3f))
              + 1e-3f*z*z*z*z;
        a4[j] = 1.5f / c_k[b];            // 2/denom == rsqrt(a4 * t_bin); weight = a4/57600
    }
    const int cl = (lane < NB) ? lane : NB-1;     // lanes>=24 broadcast col 23 (free)
    const float invcol = s_invc[cl];

    const int gw = blockIdx.x * WPB + w;
    const size_t rstep = (size_t)NWAVES * FBIN;
    size_t base0 = (size_t)gw * FBIN + bin0;

    float acc = 0.f;
    int par = 0;
    for (int r0 = gw; r0 < ROWS; r0 += 2*NWAVES) {
        const bool  v1    = (r0 + NWAVES) < ROWS;
        const float m1    = v1 ? 1.f : 0.f;
        const size_t base1 = v1 ? base0 + rstep : base0;

        // all 12 loads up front
        const float4 A0 = *(const float4*)(lm + base0), A1 = *(const float4*)(lm + base0 + 4);
        const float4 B0 = *(const float4*)(lm + base1), B1 = *(const float4*)(lm + base1 + 4);
        const float4 Ra0 = *(const float4*)(re + base0), Ra1 = *(const float4*)(re + base0 + 4);
        const float4 Rb0 = *(const float4*)(re + base1), Rb1 = *(const float4*)(re + base1 + 4);
        const float4 Ia0 = *(const float4*)(im + base0), Ia1 = *(const float4*)(im + base0 + 4);
        const float4 Ib0 = *(const float4*)(im + base1), Ib1 = *(const float4*)(im + base1 + 4);

        const float la[8] = {A0.x,A0.y,A0.z,A0.w,A1.x,A1.y,A1.z,A1.w};
        const float lb[8] = {B0.x,B0.y,B0.z,B0.w,B1.x,B1.y,B1.z,B1.w};
        float spa[8], spb[8];
        #pragma unroll
        for (int j = 0; j < 8; ++j) {
            spa[j] = __builtin_amdgcn_exp2f(fminf(la[j], 10.f) * LOG2E);
            spb[j] = __builtin_amdgcn_exp2f(fminf(lb[j], 10.f) * LOG2E);
        }

        float* const sa = &s_slot[w][par][0][0];
        float* const sb = &s_slot[w][par][1][0];
        // branchless segmented stores: cumulative rewrite, last write per slot wins
        {
            float pa = spa[0], pb = spb[0];
            sa[waddr[0]] = pa; sb[waddr[0]] = pb;
            #pragma unroll
            for (int j = 1; j < 8; ++j) {
                const bool same = (waddr[j] == waddr[j-1]);
                pa = same ? pa + spa[j] : spa[j];
                pb = same ? pb + spb[j] : spb[j];
                sa[waddr[j]] = pa; sb[waddr[j]] = pb;
            }
        }

        asm volatile("s_waitcnt lgkmcnt(0)" ::: "memory");   // own-wave store visibility

        // per-band sums (lanes 0-23): 5x b128 each row from zero-padded slots
        float psa = 0.f, psb = 0.f;
        if (lane < NB) {
            const float4* qa = (const float4*)(sa + lane*SLOTS);
            const float4* qb = (const float4*)(sb + lane*SLOTS);
            const float4 a0=qa[0],a1=qa[1],a2=qa[2],a3=qa[3],a4_=qa[4];
            const float4 b0=qb[0],b1=qb[1],b2=qb[2],b3=qb[3],b4_=qb[4];
            psa = ((((a0.x+a0.y)+(a0.z+a0.w)) + ((a1.x+a1.y)+(a1.z+a1.w)))
                +  (((a2.x+a2.y)+(a2.z+a2.w)) + ((a3.x+a3.y)+(a3.z+a3.w))))
                +   ((a4_.x+a4_.y)+(a4_.z+a4_.w));
            psb = ((((b0.x+b0.y)+(b0.z+b0.w)) + ((b1.x+b1.y)+(b1.z+b1.w)))
                +  (((b2.x+b2.y)+(b2.z+b2.w)) + ((b3.x+b3.y)+(b3.z+b3.w))))
                +   ((b4_.x+b4_.y)+(b4_.z+b4_.w));
        }

        // t = (psum@S + eps)*invcol; psums broadcast via readlane, S column from LDS
        float ta, tb;
        {
            const float* Sc = &s_Scol[cl*SCOLP];
            float a0=1e-8f,a1=0.f,a2=0.f,a3=0.f, b0=1e-8f,b1=0.f,b2=0.f,b3=0.f;
            #pragma unroll
            for (int i = 0; i < NB; i += 4) {
                const float4 q = *(const float4*)(Sc + i);
                a0 = fmaf(RDLANE(psa,i+0), q.x, a0);  b0 = fmaf(RDLANE(psb,i+0), q.x, b0);
                a1 = fmaf(RDLANE(psa,i+1), q.y, a1);  b1 = fmaf(RDLANE(psb,i+1), q.y, b1);
                a2 = fmaf(RDLANE(psa,i+2), q.z, a2);  b2 = fmaf(RDLANE(psb,i+2), q.z, b2);
                a3 = fmaf(RDLANE(psa,i+3), q.w, a3);  b3 = fmaf(RDLANE(psb,i+3), q.w, b3);
            }
            ta = ((a0+a1)+(a2+a3)) * invcol;
            tb = ((b0+b1)+(b2+b3)) * invcol;
        }

        // broadcast t[band] to all lanes (register-path, no LDS storage)
        float tba[8], tbb[8];
        #pragma unroll
        for (int j = 0; j < 8; ++j) {
            tba[j] = __int_as_float(__builtin_amdgcn_ds_bpermute(band4[j], __float_as_int(ta)));
            tbb[j] = __int_as_float(__builtin_amdgcn_ds_bpermute(band4[j], __float_as_int(tb)));
        }

        const float rva[8] = {Ra0.x,Ra0.y,Ra0.z,Ra0.w,Ra1.x,Ra1.y,Ra1.z,Ra1.w};
        const float iva[8] = {Ia0.x,Ia0.y,Ia0.z,Ia0.w,Ia1.x,Ia1.y,Ia1.z,Ia1.w};
        const float rvb[8] = {Rb0.x,Rb0.y,Rb0.z,Rb0.w,Rb1.x,Rb1.y,Rb1.z,Rb1.w};
        const float ivb[8] = {Ib0.x,Ib0.y,Ib0.z,Ib0.w,Ib1.x,Ib1.y,Ib1.z,Ib1.w};
        float accB = 0.f;
        #pragma unroll
        for (int j = 0; j < 8; ++j) {
            const float t0 = fmaxf(tba[j], tq[j]);
            const float s0 = __builtin_amdgcn_rsqf(a4[j] * t0);
            const float u0 = spa[j] * s0;
            const float pr0 = fmaf(fabsf(rva[j]), u0, 1.0f);
            const float pi0 = fmaf(fabsf(iva[j]), u0, 1.0f);
            acc  = fmaf(__builtin_amdgcn_logf(pr0 * pi0), a4[j], acc);

            const float t1 = fmaxf(tbb[j], tq[j]);
            const float s1 = __builtin_amdgcn_rsqf(a4[j] * t1);
            const float u1 = spb[j] * s1;
            const float pr1 = fmaf(fabsf(rvb[j]), u1, 1.0f);
            const float pi1 = fmaf(fabsf(ivb[j]), u1, 1.0f);
            accB = fmaf(__builtin_amdgcn_logf(pr1 * pi1), a4[j], accB);
        }
        acc = fmaf(accB, m1, acc);

        par ^= 1;                 // parity dbuf: no tail drain needed
        base0 += 2*rstep;
    }

    #pragma unroll
    for (int o = 32; o > 0; o >>= 1) acc += __shfl_xor(acc, o, 64);
    if (lane == 0) partial[gw] = acc * (1.0f/57600.0f);
}

__global__ __launch_bounds__(256) void pe_final(const float* __restrict__ partial,
                                                float* __restrict__ out)
{
    __shared__ double sred[256];
    const int tid = threadIdx.x;
    double s = 0.0;
    for (int i = tid; i < NWAVES; i += 256) s += (double)partial[i];
    sred[tid] = s;
    __syncthreads();
    for (int k = 128; k > 0; k >>= 1) {
        if (tid < k) sred[tid] += sred[tid+k];
        __syncthreads();
    }
    if (tid == 0) out[0] = (float)(1.0 / (sred[0] + 1.0));
}

extern "C" void kernel_launch(void* const* d_in, const int* in_sizes, int n_in,
                              void* d_out, int out_size, void* d_ws, size_t ws_size,
                              hipStream_t stream) {
    const float* lm = (const float*)d_in[0];
    const float* re = (const float*)d_in[1];
    const float* im = (const float*)d_in[2];
    const float* S  = (const float*)d_in[3];
    float* partial = (float*)d_ws;   // NWAVES floats = 32 KB scratch
    pe_main<<<GRID, BLK, 0, stream>>>(lm, re, im, S, partial);
    pe_final<<<1, 256, 0, stream>>>(partial, (float*)d_out);
}